// Round 2
// baseline (160.561 us; speedup 1.0000x reference)
//
#include <hip/hip_runtime.h>

// Problem constants (fixed by the reference)
#define NN   16
#define DD   3
#define HH   160
#define WW   160
#define MM   8
#define KK   10
#define PP   15
#define PM   7            // (P-1)/2
#define OUTH 146          // H - P + 1
#define OUTW 146
#define MK   (MM*KK)      // 80
#define QROW 37           // ceil(146/4) units per row (last unit clamped to x=142)
#define UNITS (OUTH*QROW) // 5402 4-px units per plane

// Load 5 consecutive floats starting at r, where (r - plane base) parity is
// block-uniform. Even: r is 8B aligned -> f2,f2,s. Odd: r+1 aligned -> s,f2,f2.
__device__ __forceinline__ void load5(const float* __restrict__ r, bool even, float c[5]) {
    if (even) {
        const float2 A = *(const float2*)(r);
        const float2 B = *(const float2*)(r + 2);
        c[0] = A.x; c[1] = A.y; c[2] = B.x; c[3] = B.y; c[4] = r[4];
    } else {
        c[0] = r[0];
        const float2 A = *(const float2*)(r + 1);
        const float2 B = *(const float2*)(r + 3);
        c[1] = A.x; c[2] = A.y; c[3] = B.x; c[4] = B.y;
    }
}

// Bilinear-sample 4 consecutive output pixels from one source row pair.
__device__ __forceinline__ void sample4(const float* __restrict__ rowptr, bool even,
                                        float fx, float fy, float p[4]) {
    float c[5], d[5];
    load5(rowptr,      even, c);
    load5(rowptr + WW, even, d);
#pragma unroll
    for (int i = 0; i < 4; ++i) {
        const float t = c[i] + fx * (c[i + 1] - c[i]);
        const float b = d[i] + fx * (d[i + 1] - d[i]);
        p[i] = t + fy * (b - t);
    }
}

__global__ __launch_bounds__(256)
void fern_bits_kernel(const float* __restrict__ T,
                      const float* __restrict__ dx1,
                      const float* __restrict__ dx2,
                      const float* __restrict__ dy1,
                      const float* __restrict__ dy2,
                      const float* __restrict__ th,
                      const float* __restrict__ amb,
                      const int*   __restrict__ channels,
                      float* __restrict__ out)
{
    const int mk = blockIdx.y;       // 0..79
    const int n  = blockIdx.z;       // 0..15
    const int k  = mk % KK;
    const int m  = mk / KK;
    const int c  = channels[k];

    // Per-feature (block-uniform) parameters
    float a, f;
    a = dx1[mk]; f = floorf(a); const float fx1 = a - f; const int sx1 = PM + (int)f;
    a = dy1[mk]; f = floorf(a); const float fy1 = a - f; const int sy1 = PM + (int)f;
    a = dx2[mk]; f = floorf(a); const float fx2 = a - f; const int sx2 = PM + (int)f;
    a = dy2[mk]; f = floorf(a); const float fy2 = a - f; const int sy2 = PM + (int)f;
    const float thv = th[mk];
    const float pos = amb[(m*2 + 0)*KK + k];
    const float neg = amb[(m*2 + 1)*KK + k];
    const float scl = 1.0f / (pos - neg + 1e-29f);
    const bool  ev1 = ((sx1 & 1) == 0);
    const bool  ev2 = ((sx2 & 1) == 0);

    const float* __restrict__ Tp = T + (size_t)(n*DD + c) * (HH*WW);

    const unsigned u = blockIdx.x * 256u + threadIdx.x;
    if (u >= UNITS) return;
    const unsigned y = u / QROW;
    const unsigned q = u - y * QROW;
    int x = (int)q * 4;
    if (q == QROW - 1) x = OUTW - 4;   // clamp tail: re-writes identical values

    float p1[4], p2[4];
    sample4(Tp + (sy1 + (int)y) * WW + (sx1 + x), ev1, fx1, fy1, p1);
    sample4(Tp + (sy2 + (int)y) * WW + (sx2 + x), ev2, fx2, fy2, p2);

    float o[4];
#pragma unroll
    for (int i = 0; i < 4; ++i) {
        float t = p1[i] - p2[i];
        if (fabsf(t) < 1e-5f) t = 0.0f;
        o[i] = fminf(fmaxf((t - thv - neg) * scl, 0.0f), 1.0f);
    }

    const size_t oidx = ((size_t)(n * MK + mk) * OUTH + y) * OUTW + x;
    float* dst = out + oidx;            // x even -> 8B aligned (row stride 584B)
    *(float2*)(dst)     = make_float2(o[0], o[1]);
    *(float2*)(dst + 2) = make_float2(o[2], o[3]);
}

extern "C" void kernel_launch(void* const* d_in, const int* in_sizes, int n_in,
                              void* d_out, int out_size, void* d_ws, size_t ws_size,
                              hipStream_t stream) {
    const float* T        = (const float*)d_in[0];
    const float* dx1      = (const float*)d_in[1];
    const float* dx2      = (const float*)d_in[2];
    const float* dy1      = (const float*)d_in[3];
    const float* dy2      = (const float*)d_in[4];
    const float* th       = (const float*)d_in[5];
    const float* amb      = (const float*)d_in[6];
    const int*   channels = (const int*)d_in[7];
    float* out = (float*)d_out;

    dim3 grid((UNITS + 255) / 256, MK, NN);
    dim3 block(256, 1, 1);
    fern_bits_kernel<<<grid, block, 0, stream>>>(T, dx1, dx2, dy1, dy2, th, amb,
                                                 channels, out);
}

// Round 4
// 158.460 us; speedup vs baseline: 1.0133x; 1.0133x over previous
//
#include <hip/hip_runtime.h>

// Problem constants (fixed by the reference)
#define NN   16
#define DD   3
#define HH   160
#define WW   160
#define MM   8
#define KK   10
#define PP   15
#define PM   7            // (P-1)/2
#define OUTH 146          // H - P + 1
#define OUTW 146
#define MK   (MM*KK)      // 80
#define QROW 19           // ceil(146/8) 8-px units per row (last clamped to x=138)
#define UNITS (OUTH*QROW) // 2774 units per plane

typedef float vf2 __attribute__((ext_vector_type(2)));  // native vec for nt-store

// Load 9 consecutive floats starting at r, where parity of (r - base) is
// block-uniform. Even: r 8B aligned -> 4x float2 + scalar. Odd: scalar + 4x float2.
__device__ __forceinline__ void load9(const float* __restrict__ r, bool even, float c[9]) {
    if (even) {
        const vf2 A = *(const vf2*)(r);
        const vf2 B = *(const vf2*)(r + 2);
        const vf2 C = *(const vf2*)(r + 4);
        const vf2 D = *(const vf2*)(r + 6);
        c[0]=A.x; c[1]=A.y; c[2]=B.x; c[3]=B.y;
        c[4]=C.x; c[5]=C.y; c[6]=D.x; c[7]=D.y; c[8]=r[8];
    } else {
        c[0] = r[0];
        const vf2 A = *(const vf2*)(r + 1);
        const vf2 B = *(const vf2*)(r + 3);
        const vf2 C = *(const vf2*)(r + 5);
        const vf2 D = *(const vf2*)(r + 7);
        c[1]=A.x; c[2]=A.y; c[3]=B.x; c[4]=B.y;
        c[5]=C.x; c[6]=C.y; c[7]=D.x; c[8]=D.y;
    }
}

// Bilinear-sample 8 consecutive output pixels from one source row pair.
__device__ __forceinline__ void sample8(const float* __restrict__ rowptr, bool even,
                                        float fx, float fy, float p[8]) {
    float c[9], d[9];
    load9(rowptr,      even, c);
    load9(rowptr + WW, even, d);
#pragma unroll
    for (int i = 0; i < 8; ++i) {
        const float t = c[i] + fx * (c[i + 1] - c[i]);
        const float b = d[i] + fx * (d[i + 1] - d[i]);
        p[i] = t + fy * (b - t);
    }
}

__global__ __launch_bounds__(256)
void fern_bits_kernel(const float* __restrict__ T,
                      const float* __restrict__ dx1,
                      const float* __restrict__ dx2,
                      const float* __restrict__ dy1,
                      const float* __restrict__ dy2,
                      const float* __restrict__ th,
                      const float* __restrict__ amb,
                      const int*   __restrict__ channels,
                      float* __restrict__ out)
{
    const int mk = blockIdx.y;       // 0..79
    const int n  = blockIdx.z;       // 0..15
    const int k  = mk % KK;
    const int m  = mk / KK;
    const int c  = channels[k];

    // Per-feature (block-uniform) parameters
    float a, f;
    a = dx1[mk]; f = floorf(a); const float fx1 = a - f; const int sx1 = PM + (int)f;
    a = dy1[mk]; f = floorf(a); const float fy1 = a - f; const int sy1 = PM + (int)f;
    a = dx2[mk]; f = floorf(a); const float fx2 = a - f; const int sx2 = PM + (int)f;
    a = dy2[mk]; f = floorf(a); const float fy2 = a - f; const int sy2 = PM + (int)f;
    const float pos = amb[(m*2 + 0)*KK + k];
    const float neg = amb[(m*2 + 1)*KK + k];
    const float off = th[mk] + neg;                 // folded: (t - th - neg)
    const float scl = 1.0f / (pos - neg + 1e-29f);
    const bool  ev1 = ((sx1 & 1) == 0);
    const bool  ev2 = ((sx2 & 1) == 0);

    const float* __restrict__ Tp = T + (size_t)(n*DD + c) * (HH*WW);

    const unsigned u = blockIdx.x * 256u + threadIdx.x;
    if (u >= UNITS) return;
    const unsigned y = u / QROW;
    const unsigned q = u - y * QROW;
    int x = (int)q * 8;
    if (q == QROW - 1) x = OUTW - 8;   // clamp tail: overlapping identical re-writes

    float p1[8], p2[8];
    sample8(Tp + (sy1 + (int)y) * WW + (sx1 + x), ev1, fx1, fy1, p1);
    sample8(Tp + (sy2 + (int)y) * WW + (sx2 + x), ev2, fx2, fy2, p2);

    float o[8];
#pragma unroll
    for (int i = 0; i < 8; ++i) {
        float t = p1[i] - p2[i];
        if (fabsf(t) < 1e-5f) t = 0.0f;
        o[i] = fminf(fmaxf((t - off) * scl, 0.0f), 1.0f);
    }

    const size_t oidx = ((size_t)(n * MK + mk) * OUTH + y) * OUTW + x;
    float* dst = out + oidx;            // x even -> 8B aligned (row stride 584B)
#pragma unroll
    for (int i = 0; i < 4; ++i) {
        vf2 v; v.x = o[2*i]; v.y = o[2*i+1];
        __builtin_nontemporal_store(v, (vf2*)(dst + 2*i));
    }
}

extern "C" void kernel_launch(void* const* d_in, const int* in_sizes, int n_in,
                              void* d_out, int out_size, void* d_ws, size_t ws_size,
                              hipStream_t stream) {
    const float* T        = (const float*)d_in[0];
    const float* dx1      = (const float*)d_in[1];
    const float* dx2      = (const float*)d_in[2];
    const float* dy1      = (const float*)d_in[3];
    const float* dy2      = (const float*)d_in[4];
    const float* th       = (const float*)d_in[5];
    const float* amb      = (const float*)d_in[6];
    const int*   channels = (const int*)d_in[7];
    float* out = (float*)d_out;

    dim3 grid((UNITS + 255) / 256, MK, NN);
    dim3 block(256, 1, 1);
    fern_bits_kernel<<<grid, block, 0, stream>>>(T, dx1, dx2, dy1, dy2, th, amb,
                                                 channels, out);
}